// Round 20
// baseline (90.305 us; speedup 1.0000x reference)
//
#include <hip/hip_runtime.h>
#include <math.h>

#define NSTEP  730
#define NGRID  1500
#define LENF   15
#define PRECS  1e-5f
#define CH     16
#define NCHUNK 46                  // 45 full chunks + tail of 10
#define NPHASE (NCHUNK+3)          // 4-stage pipeline fill/drain
#define QROW   260                 // 64 float4 = 256 dw + 4 pad
#define OTW    21                  // out-tile row: 20 + 1 pad

static __device__ __forceinline__ float flog2(float v){ return __builtin_amdgcn_logf(v); }

// LDS-only barrier (R19, kept): lgkmcnt(0) + s_barrier, no vmcnt drain.
#define PIPE_BARRIER() do { \
    asm volatile("s_waitcnt lgkmcnt(0)" ::: "memory"); \
    __builtin_amdgcn_sched_barrier(0); \
    __builtin_amdgcn_s_barrier(); \
    __builtin_amdgcn_sched_barrier(0); \
} while(0)

// Block = 256 threads = 4 waves = 4 pipeline stages over 4 grids, 375 blocks.
// R20: W1's HW transcendentals (v_log_f32/v_exp_f32, ~70-80cyc latency each at
// 1 wave/SIMD — the measured 185cyc/step serial wall) are replaced by
// short-latency polynomial forms (Estrin, depth 3-4 fma). Everything else
// is frozen at R19 for clean attribution.
__global__ __launch_bounds__(256, 1)
void hbv_scan_kernel(const float* __restrict__ x,       // (730,1500,3)
                     const float* __restrict__ params,  // (1500,12,16)
                     const float* __restrict__ rtwts,   // (1500,2)
                     float* __restrict__ out)           // (730,1500,5)
{
    __shared__ float  xring[3*CH*16];    //  3.0 KB (slot c%3)
    __shared__ float  rtbuf[2*CH*64];    //  8.0 KB
    __shared__ float2 soilbuf[2*CH*64];  // 16.0 KB (re, ETact)
    __shared__ float  qbuf[2*CH*QROW];   // 32.5 KB
    __shared__ float  outtile[CH*OTW];   //  1.3 KB
    __shared__ float  ring[4*64];        //  1.0 KB  (total ~62 KB, 2 blocks/CU)

    const int tid  = threadIdx.x;
    const int wid  = tid >> 6;
    const int lane = tid & 63;
    const int gl = lane >> 4, m = lane & 15;
    const int b  = blockIdx.x;
    const int g  = b*4 + gl;
    const float inv16 = 1.f/16.f;

    // prestage chunk 0 (W3) + zero conv ring, one uniform barrier
    if (wid == 3) {
        #pragma unroll
        for (int j = 0; j < 3; ++j) {
            const int idx = lane + 64*j;
            const int r = idx/12, rem = idx - 12*r;
            const int gi = rem/3, ch = rem - 3*gi;
            xring[r*16 + gi*4 + ch] = x[r*4500 + b*12 + gi*3 + ch];
        }
    }
    ring[tid & 255] = 0.f;
    PIPE_BARRIER();

    if (wid == 0) {
        // ================= W0: snow recursion =================
        const float pTT     = -2.5f + params[(g*12+8)*16+m]*5.f;
        const float pCFMAX  =  0.5f + params[(g*12+9)*16+m]*9.5f;
        const float refCoef = (params[(g*12+10)*16+m]*0.1f)*pCFMAX;
        const float pCWH    =          params[(g*12+11)*16+m]*0.2f;
        const float negCMTT = -pCFMAX*pTT;
        const float refCTT  = refCoef*pTT;
        float SP = 0.001f, MW = 0.001f;
        for (int p = 0; p < NPHASE; ++p) {
            if (p < NCHUNK) {
                const float* xb = &xring[(p%3)*CH*16 + gl*4];
                float* rb = &rtbuf[(p&1)*CH*64 + lane];
                float2 PT[CH];
                #pragma unroll
                for (int s = 0; s < CH; ++s)
                    PT[s] = *(const float2*)(xb + s*16);
                #pragma unroll
                for (int s = 0; s < CH; ++s) {
                    const float Pm = PT[s].x, Tm = PT[s].y;
                    const float RAIN    = (Tm >= pTT) ? Pm : 0.f;
                    const float meltcap = fmaxf(fmaf(pCFMAX, Tm, negCMTT), 0.f);
                    const float refcap  = fmaxf(fmaf(-refCoef, Tm, refCTT), 0.f);
                    const float SP1 = SP + (Pm - RAIN);
                    const float melt = fminf(meltcap, SP1);
                    const float MW1 = MW + melt;
                    const float refreeze = fminf(refcap, MW1);
                    SP = SP1 - melt + refreeze;
                    const float MW2 = MW1 - refreeze;
                    const float tosoil = fmaxf(fmaf(-pCWH, SP, MW2), 0.f);
                    MW = MW2 - tosoil;
                    rb[s*64] = RAIN + tosoil;
                }
            }
            PIPE_BARRIER();
        }
    } else if (wid == 1) {
        // ===== W1: soil (SM) recursion — polynomial pow (short latency) =====
        const float bb  = 1.f  + params[(g*12+0)*16+m]*5.f;
        const float pFC = 50.f + params[(g*12+1)*16+m]*950.f;
        const float pLP = 0.2f + params[(g*12+5)*16+m]*0.8f;
        const float iLPFC = 1.f/(pLP*pFC);
        const float cc = -bb * flog2(pFC);       // one-time, HW log2 is fine
        // log2 mantissa poly (deg-8 Taylor, t in [-0.25,0.5))
        const float C1= 1.44269504f, C2=-0.72134752f, C3= 0.48089835f,
                    C4=-0.36067376f, C5= 0.28853901f, C6=-0.24044917f,
                    C7= 0.20609929f, C8=-0.18033688f;
        // exp2 frac poly (deg-6 Taylor, f in [0,1))
        const float E1= 0.69314718f, E2= 0.24022651f, E3= 0.05550411f,
                    E4= 0.00961813f, E5= 0.00133336f, E6= 0.00015404f;
        float SM = 0.001f;
        for (int p = 0; p < NPHASE; ++p) {
            if (p >= 1 && p-1 < NCHUNK) {
                const int c = p-1;
                const float* xe = &xring[(c%3)*CH*16 + gl*4 + 2];
                const float* rb = &rtbuf[(c&1)*CH*64 + lane];
                float2* sb = &soilbuf[(c&1)*CH*64 + lane];
                float rt[CH], Ev[CH];
                #pragma unroll
                for (int s = 0; s < CH; ++s) { rt[s] = rb[s*64]; Ev[s] = xe[s*16]; }
                #pragma unroll
                for (int s = 0; s < CH; ++s) {
                    // ---- sw = (SM/FC)^bb = exp2(bb*log2(SM) + cc), poly form ----
                    const int   ii = __float_as_int(SM);
                    const int   eI = ((ii + 0x00400000) >> 23) - 127; // rounded exp
                    const float mf = __int_as_float(ii - (eI << 23)); // [0.75,1.5)
                    const float t  = mf - 1.f;
                    const float t2 = t*t;
                    const float t4 = t2*t2;
                    const float p01 = fmaf(C2, t, C1);
                    const float p23 = fmaf(C4, t, C3);
                    const float p45 = fmaf(C6, t, C5);
                    const float p67 = fmaf(C8, t, C7);
                    const float q0  = fmaf(p23, t2, p01);
                    const float q1  = fmaf(p67, t2, p45);
                    const float Rp  = fmaf(q1, t4, q0);
                    const float P   = t * Rp;                         // log2(mf)
                    const float base= fmaf(bb, (float)eI, cc);        // parallel
                    const float v   = fmaf(bb, P, base);              // <= ~0
                    const float fl  = floorf(v);
                    const float f   = v - fl;
                    const float f2  = f*f;
                    const float f4  = f2*f2;
                    const float a01 = fmaf(E1, f, 1.f);
                    const float a23 = fmaf(E3, f, E2);
                    const float a45 = fmaf(E5, f, E4);
                    const float b0  = fmaf(a23, f2, a01);
                    const float b1  = fmaf(E6, f2, a45);
                    const float Qp  = fmaf(b1, f4, b0);               // 2^f
                    int ei = (int)fl + 127; ei = (ei < 0) ? 0 : ei;   // underflow->0
                    const float sw  = __int_as_float(ei << 23) * Qp;

                    // ---- rest of soil step (max3/min3 fused forms) ----
                    const float SM1 = fmaf(-rt[s], sw, SM + rt[s]);
                    const float SM2 = fminf(SM1, pFC);
                    const float cE  = Ev[s] * iLPFC;
                    const float et  = fminf(fminf(SM2*cE, SM2), Ev[s]);  // v_min3
                    const float re  = fmaf(rt[s], sw, SM1 - SM2);
                    SM = fmaxf(fmaxf(fmaf(-SM2, cE, SM2), SM2 - Ev[s]), PRECS);
                    sb[s*64] = make_float2(re, et);
                }
            }
            PIPE_BARRIER();
        }
    } else if (wid == 2) {
        // ================= W2: response (SUZ,SLZ) recursion =================
        const float pK0   = 0.05f  + params[(g*12+2)*16+m]*0.85f;
        const float pK1   = 0.01f  + params[(g*12+3)*16+m]*0.49f;
        const float pK2   = 0.001f + params[(g*12+4)*16+m]*0.199f;
        const float pPERC =          params[(g*12+6)*16+m]*10.f;
        const float pUZL  =          params[(g*12+7)*16+m]*100.f;
        const float oneMinusK0 = 1.f - pK0, K0UZL = pK0*pUZL;
        float SUZ = 0.001f, SLZ = 0.001f;
        for (int p = 0; p < NPHASE; ++p) {
            if (p >= 2 && p-2 < NCHUNK) {
                const int c = p-2;
                const float2* sb = &soilbuf[(c&1)*CH*64 + lane];
                float* qb = &qbuf[(c&1)*CH*QROW + lane*4];
                float2 rE[CH];
                #pragma unroll
                for (int s = 0; s < CH; ++s) rE[s] = sb[s*64];
                #pragma unroll
                for (int s = 0; s < CH; ++s) {
                    const float SUZ1 = SUZ + rE[s].x;
                    const float SUZ2 = fmaxf(SUZ1 - pPERC, 0.f);
                    const float PERC = SUZ1 - SUZ2;
                    const float SUZ3 = fminf(SUZ2, fmaf(SUZ2, oneMinusK0, K0UZL));
                    const float Q0 = SUZ2 - SUZ3;
                    const float Q1 = pK1 * SUZ3;
                    SUZ = SUZ3 - Q1;
                    const float SLZ1 = SLZ + PERC;
                    const float Q2 = pK2 * SLZ1;
                    SLZ = SLZ1 - Q2;
                    *(float4*)(qb + s*QROW) = make_float4(Q0, Q1, Q2, rE[s].y);
                }
            }
            PIPE_BARRIER();
        }
    } else {
        // ================= W3: epilogue + x staging =================
        float wq[LENF];
        {
            const float ta  = rtwts[g*2+0] * 2.9f;
            const float tbv = rtwts[g*2+1] * 6.5f;
            const float aa = fmaxf(ta, 0.f) + 0.1f;
            const float th = fmaxf(tbv, 0.f) + 0.5f;
            const float c0v = expf(-lgammaf(aa)) * powf(th, -aa);
            float wsum = 0.f;
            #pragma unroll
            for (int k = 0; k < LENF; ++k) {
                const float tt = (float)k + 0.5f;
                wq[k] = c0v * powf(tt, aa-1.f) * expf(-tt/th);
                wsum += wq[k];
            }
            const float ws = inv16 / wsum;
            #pragma unroll
            for (int k = 0; k < LENF; ++k) wq[k] *= ws;
        }
        int rbase[3], bcol[3], lslot[3];
        #pragma unroll
        for (int j = 0; j < 3; ++j) {
            const int idx = lane + 64*j;
            const int r = idx/12, rem = idx - 12*r;
            const int gi = rem/3, ch = rem - 3*gi;
            rbase[j] = r;
            bcol[j]  = b*12 + gi*3 + ch;
            lslot[j] = r*16 + gi*4 + ch;
        }
        int st_o[5], st_g[5];
        #pragma unroll
        for (int j = 0; j < 5; ++j) {
            const int idx = lane + 64*j;
            const int tt = idx/20, cl = idx - 20*tt;
            st_o[j] = tt*OTW + cl;
            st_g[j] = tt*7500 + cl;
        }

        for (int p = 0; p < NPHASE; ++p) {
            const bool do_stage = (p+1 < NCHUNK);
            float stg0=0.f, stg1=0.f, stg2=0.f;
            if (do_stage) {
                int r0 = (p+1)*CH + rbase[0]; r0 = (r0 < NSTEP) ? r0 : (NSTEP-1);
                int r1 = (p+1)*CH + rbase[1]; r1 = (r1 < NSTEP) ? r1 : (NSTEP-1);
                int r2 = (p+1)*CH + rbase[2]; r2 = (r2 < NSTEP) ? r2 : (NSTEP-1);
                stg0 = x[r0*4500 + bcol[0]];
                stg1 = x[r1*4500 + bcol[1]];
                stg2 = x[r2*4500 + bcol[2]];
            }
            const int q = p - 3;
            if (q >= 0) {
                const int nstep = (q == NCHUNK-1) ? (NSTEP - (NCHUNK-1)*CH) : CH;
                const float* qb = &qbuf[(q&1)*CH*QROW];
                const int t = q*CH + m;
                float a0=0.f, a1=0.f, a2=0.f, a3=0.f;
                if (m < nstep) {
                    float4 v[16];
                    #pragma unroll
                    for (int i = 0; i < 16; ++i)
                        v[i] = *(const float4*)&qb[m*QROW + gl*64 + i*4];
                    float4 s0 = v[0], s1 = v[1], s2 = v[2], s3 = v[3];
                    #pragma unroll
                    for (int i = 4; i < 16; i += 4) {
                        s0.x+=v[i].x;   s0.y+=v[i].y;   s0.z+=v[i].z;   s0.w+=v[i].w;
                        s1.x+=v[i+1].x; s1.y+=v[i+1].y; s1.z+=v[i+1].z; s1.w+=v[i+1].w;
                        s2.x+=v[i+2].x; s2.y+=v[i+2].y; s2.z+=v[i+2].z; s2.w+=v[i+2].w;
                        s3.x+=v[i+3].x; s3.y+=v[i+3].y; s3.z+=v[i+3].z; s3.w+=v[i+3].w;
                    }
                    a0 = (s0.x+s1.x) + (s2.x+s3.x);
                    a1 = (s0.y+s1.y) + (s2.y+s3.y);
                    a2 = (s0.z+s1.z) + (s2.z+s3.z);
                    a3 = (s0.w+s1.w) + (s2.w+s3.w);
                    ring[gl*64 + (t & 63)] = a0 + a1 + a2;
                }
                asm volatile("s_waitcnt lgkmcnt(0)" ::: "memory");
                if (m < nstep) {
                    float rv[LENF];
                    #pragma unroll
                    for (int k = 0; k < LENF; ++k)
                        rv[k] = ring[gl*64 + ((t - k) & 63)];
                    float accA = 0.f, accB = 0.f;
                    #pragma unroll
                    for (int k = 0; k < LENF-1; k += 2) {
                        accA = fmaf(wq[k],   rv[k],   accA);
                        accB = fmaf(wq[k+1], rv[k+1], accB);
                    }
                    accA = fmaf(wq[LENF-1], rv[LENF-1], accA);
                    float* ot = &outtile[m*OTW + gl*5];
                    ot[0] = accA + accB;
                    ot[1] = a0*inv16; ot[2] = a1*inv16;
                    ot[3] = a2*inv16; ot[4] = a3*inv16;
                }
                asm volatile("s_waitcnt lgkmcnt(0)" ::: "memory");
                const int ndw = nstep*20;
                float* ob = out + q*CH*7500 + b*20;
                #pragma unroll
                for (int j = 0; j < 5; ++j) {
                    const int idx = lane + 64*j;
                    if (idx < ndw) ob[st_g[j]] = outtile[st_o[j]];
                }
            }
            if (do_stage) {
                float* xd = &xring[((p+1)%3)*CH*16];
                xd[lslot[0]] = stg0; xd[lslot[1]] = stg1; xd[lslot[2]] = stg2;
            }
            PIPE_BARRIER();
        }
    }
}

extern "C" void kernel_launch(void* const* d_in, const int* in_sizes, int n_in,
                              void* d_out, int out_size, void* d_ws, size_t ws_size,
                              hipStream_t stream)
{
    const float* x      = (const float*)d_in[0];
    const float* params = (const float*)d_in[1];
    const float* rt     = (const float*)d_in[2];
    float* out = (float*)d_out;

    dim3 grid(NGRID / 4), block(256);
    hipLaunchKernelGGL(hbv_scan_kernel, grid, block, 0, stream, x, params, rt, out);
}

// Round 21
// 70.598 us; speedup vs baseline: 1.2791x; 1.2791x over previous
//
#include <hip/hip_runtime.h>
#include <math.h>

#define NSTEP  730
#define NGRID  1500
#define LENF   15
#define PRECS  1e-5f
#define CH     16
#define NCHUNK 46                  // 45 full chunks + tail of 10
#define NPHASE (NCHUNK+3)          // 4-stage pipeline fill/drain
#define QROW   260                 // 64 float4 = 256 dw + 4 pad
#define OTW    21                  // out-tile row: 20 + 1 pad

static __device__ __forceinline__ float fexp2(float v){ return __builtin_amdgcn_exp2f(v); }
static __device__ __forceinline__ float flog2(float v){ return __builtin_amdgcn_logf(v); }

// LDS-only barrier (R19): lgkmcnt(0) + s_barrier, no vmcnt drain.
#define PIPE_BARRIER() do { \
    asm volatile("s_waitcnt lgkmcnt(0)" ::: "memory"); \
    __builtin_amdgcn_sched_barrier(0); \
    __builtin_amdgcn_s_barrier(); \
    __builtin_amdgcn_sched_barrier(0); \
} while(0)

// Block = 512 threads = TWO complete 4-wave pipelines (A: waves 0-3, B: 4-7),
// 8 grids/block, 188 blocks, 1 block/CU (LDS ~127KB). Waves map to SIMDs as
// wave_id%4, so BOTH W1 (soil/pow) waves land on SIMD1 of every CU: their
// serial chains interleave and hide each other's ~12cyc/dep exposed latency
// (the R14-R20 wall). Per-pipeline structure is frozen at R19.
__global__ __launch_bounds__(512, 1)
void hbv_scan_kernel(const float* __restrict__ x,       // (730,1500,3)
                     const float* __restrict__ params,  // (1500,12,16)
                     const float* __restrict__ rtwts,   // (1500,2)
                     float* __restrict__ out)           // (730,1500,5)
{
    __shared__ float  xringA[2][3*CH*16];    //  2 ×  3.0 KB
    __shared__ float  rtbufA[2][2*CH*64];    //  2 ×  8.0 KB
    __shared__ float2 soilA [2][2*CH*64];    //  2 × 16.0 KB
    __shared__ float  qbufA [2][2*CH*QROW];  //  2 × 32.5 KB
    __shared__ float  outtA [2][CH*OTW];     //  2 ×  1.3 KB
    __shared__ float  ringA [2][4*64];       //  2 ×  1.0 KB  (total ~127 KB)

    const int tid  = threadIdx.x;
    const int pipe = tid >> 8;               // 0: waves 0-3, 1: waves 4-7
    const int wid  = (tid >> 6) & 3;         // stage within pipeline
    const int lane = tid & 63;
    const int gl = lane >> 4, m = lane & 15;
    const int b  = blockIdx.x;
    const int g  = b*8 + pipe*4 + gl;        // may be phantom 1500-1503
    const int gc = (g < NGRID) ? g : (NGRID-1);
    const float inv16 = 1.f/16.f;

    float*  xring   = xringA[pipe];
    float*  rtbuf   = rtbufA[pipe];
    float2* soilbuf = soilA[pipe];
    float*  qbuf    = qbufA[pipe];
    float*  outtile = outtA[pipe];
    float*  ring    = ringA[pipe];

    // prestage chunk 0 (each pipe's W3) + zero conv ring, one uniform barrier
    if (wid == 3) {
        #pragma unroll
        for (int j = 0; j < 3; ++j) {
            const int idx = lane + 64*j;
            const int r = idx/12, rem = idx - 12*r;
            const int gi = rem/3, ch = rem - 3*gi;
            int col = b*24 + pipe*12 + gi*3 + ch;
            if (col >= 4500) col = 4497 + ch;            // phantom -> grid 1499
            xring[r*16 + gi*4 + ch] = x[r*4500 + col];
        }
    }
    ring[tid & 255] = 0.f;
    PIPE_BARRIER();

    if (wid == 0) {
        // ================= W0: snow recursion =================
        const float pTT     = -2.5f + params[(gc*12+8)*16+m]*5.f;
        const float pCFMAX  =  0.5f + params[(gc*12+9)*16+m]*9.5f;
        const float refCoef = (params[(gc*12+10)*16+m]*0.1f)*pCFMAX;
        const float pCWH    =          params[(gc*12+11)*16+m]*0.2f;
        const float negCMTT = -pCFMAX*pTT;
        const float refCTT  = refCoef*pTT;
        float SP = 0.001f, MW = 0.001f;
        for (int p = 0; p < NPHASE; ++p) {
            if (p < NCHUNK) {
                const float* xb = &xring[(p%3)*CH*16 + gl*4];
                float* rb = &rtbuf[(p&1)*CH*64 + lane];
                float2 PT[CH];
                #pragma unroll
                for (int s = 0; s < CH; ++s)
                    PT[s] = *(const float2*)(xb + s*16);
                #pragma unroll
                for (int s = 0; s < CH; ++s) {
                    const float Pm = PT[s].x, Tm = PT[s].y;
                    const float RAIN    = (Tm >= pTT) ? Pm : 0.f;
                    const float meltcap = fmaxf(fmaf(pCFMAX, Tm, negCMTT), 0.f);
                    const float refcap  = fmaxf(fmaf(-refCoef, Tm, refCTT), 0.f);
                    const float SP1 = SP + (Pm - RAIN);
                    const float melt = fminf(meltcap, SP1);
                    const float MW1 = MW + melt;
                    const float refreeze = fminf(refcap, MW1);
                    SP = SP1 - melt + refreeze;
                    const float MW2 = MW1 - refreeze;
                    const float tosoil = fmaxf(fmaf(-pCWH, SP, MW2), 0.f);
                    MW = MW2 - tosoil;
                    rb[s*64] = RAIN + tosoil;
                }
            }
            PIPE_BARRIER();
        }
    } else if (wid == 1) {
        // ================= W1: soil (SM) recursion =================
        const float bb  = 1.f  + params[(gc*12+0)*16+m]*5.f;
        const float pFC = 50.f + params[(gc*12+1)*16+m]*950.f;
        const float pLP = 0.2f + params[(gc*12+5)*16+m]*0.8f;
        const float iLPFC = 1.f/(pLP*pFC);
        const float cc = -bb * flog2(pFC);       // sw = exp2(bb*log2(SM)+cc)
        float SM = 0.001f;
        for (int p = 0; p < NPHASE; ++p) {
            if (p >= 1 && p-1 < NCHUNK) {
                const int c = p-1;
                const float* xe = &xring[(c%3)*CH*16 + gl*4 + 2];
                const float* rb = &rtbuf[(c&1)*CH*64 + lane];
                float2* sb = &soilbuf[(c&1)*CH*64 + lane];
                float rt[CH], Ev[CH];
                #pragma unroll
                for (int s = 0; s < CH; ++s) { rt[s] = rb[s*64]; Ev[s] = xe[s*16]; }
                #pragma unroll
                for (int s = 0; s < CH; ++s) {
                    const float sw  = fexp2(fmaf(bb, flog2(SM), cc));
                    const float SM1 = fmaf(-rt[s], sw, SM + rt[s]);
                    const float SM2 = fminf(SM1, pFC);
                    const float cE  = Ev[s] * iLPFC;
                    const float et  = fminf(fminf(SM2*cE, SM2), Ev[s]);  // v_min3
                    const float re  = fmaf(rt[s], sw, SM1 - SM2);
                    SM = fmaxf(fmaxf(fmaf(-SM2, cE, SM2), SM2 - Ev[s]), PRECS);
                    sb[s*64] = make_float2(re, et);
                }
            }
            PIPE_BARRIER();
        }
    } else if (wid == 2) {
        // ================= W2: response (SUZ,SLZ) recursion =================
        const float pK0   = 0.05f  + params[(gc*12+2)*16+m]*0.85f;
        const float pK1   = 0.01f  + params[(gc*12+3)*16+m]*0.49f;
        const float pK2   = 0.001f + params[(gc*12+4)*16+m]*0.199f;
        const float pPERC =          params[(gc*12+6)*16+m]*10.f;
        const float pUZL  =          params[(gc*12+7)*16+m]*100.f;
        const float oneMinusK0 = 1.f - pK0, K0UZL = pK0*pUZL;
        float SUZ = 0.001f, SLZ = 0.001f;
        for (int p = 0; p < NPHASE; ++p) {
            if (p >= 2 && p-2 < NCHUNK) {
                const int c = p-2;
                const float2* sb = &soilbuf[(c&1)*CH*64 + lane];
                float* qb = &qbuf[(c&1)*CH*QROW + lane*4];
                float2 rE[CH];
                #pragma unroll
                for (int s = 0; s < CH; ++s) rE[s] = sb[s*64];
                #pragma unroll
                for (int s = 0; s < CH; ++s) {
                    const float SUZ1 = SUZ + rE[s].x;
                    const float SUZ2 = fmaxf(SUZ1 - pPERC, 0.f);
                    const float PERC = SUZ1 - SUZ2;
                    const float SUZ3 = fminf(SUZ2, fmaf(SUZ2, oneMinusK0, K0UZL));
                    const float Q0 = SUZ2 - SUZ3;
                    const float Q1 = pK1 * SUZ3;
                    SUZ = SUZ3 - Q1;
                    const float SLZ1 = SLZ + PERC;
                    const float Q2 = pK2 * SLZ1;
                    SLZ = SLZ1 - Q2;
                    *(float4*)(qb + s*QROW) = make_float4(Q0, Q1, Q2, rE[s].y);
                }
            }
            PIPE_BARRIER();
        }
    } else {
        // ================= W3: epilogue + x staging =================
        float wq[LENF];
        {
            const float ta  = rtwts[gc*2+0] * 2.9f;
            const float tbv = rtwts[gc*2+1] * 6.5f;
            const float aa = fmaxf(ta, 0.f) + 0.1f;
            const float th = fmaxf(tbv, 0.f) + 0.5f;
            const float c0v = expf(-lgammaf(aa)) * powf(th, -aa);
            float wsum = 0.f;
            #pragma unroll
            for (int k = 0; k < LENF; ++k) {
                const float tt = (float)k + 0.5f;
                wq[k] = c0v * powf(tt, aa-1.f) * expf(-tt/th);
                wsum += wq[k];
            }
            const float ws = inv16 / wsum;
            #pragma unroll
            for (int k = 0; k < LENF; ++k) wq[k] *= ws;
        }
        int rbase[3], bcol[3], lslot[3];
        #pragma unroll
        for (int j = 0; j < 3; ++j) {
            const int idx = lane + 64*j;
            const int r = idx/12, rem = idx - 12*r;
            const int gi = rem/3, ch = rem - 3*gi;
            rbase[j] = r;
            int col = b*24 + pipe*12 + gi*3 + ch;
            if (col >= 4500) col = 4497 + ch;            // phantom -> grid 1499
            bcol[j]  = col;
            lslot[j] = r*16 + gi*4 + ch;
        }
        int st_o[5], st_g[5], st_ok[5];
        #pragma unroll
        for (int j = 0; j < 5; ++j) {
            const int idx = lane + 64*j;
            const int tt = idx/20, cl = idx - 20*tt;
            st_o[j] = tt*OTW + cl;
            st_g[j] = tt*7500 + cl;
            st_ok[j] = (b*40 + pipe*20 + cl < 7500);     // mask phantom cols
        }

        for (int p = 0; p < NPHASE; ++p) {
            const bool do_stage = (p+1 < NCHUNK);
            float stg0=0.f, stg1=0.f, stg2=0.f;
            if (do_stage) {
                int r0 = (p+1)*CH + rbase[0]; r0 = (r0 < NSTEP) ? r0 : (NSTEP-1);
                int r1 = (p+1)*CH + rbase[1]; r1 = (r1 < NSTEP) ? r1 : (NSTEP-1);
                int r2 = (p+1)*CH + rbase[2]; r2 = (r2 < NSTEP) ? r2 : (NSTEP-1);
                stg0 = x[r0*4500 + bcol[0]];
                stg1 = x[r1*4500 + bcol[1]];
                stg2 = x[r2*4500 + bcol[2]];
            }
            const int q = p - 3;
            if (q >= 0) {
                const int nstep = (q == NCHUNK-1) ? (NSTEP - (NCHUNK-1)*CH) : CH;
                const float* qb = &qbuf[(q&1)*CH*QROW];
                const int t = q*CH + m;
                float a0=0.f, a1=0.f, a2=0.f, a3=0.f;
                if (m < nstep) {
                    float4 v[16];
                    #pragma unroll
                    for (int i = 0; i < 16; ++i)
                        v[i] = *(const float4*)&qb[m*QROW + gl*64 + i*4];
                    float4 s0 = v[0], s1 = v[1], s2 = v[2], s3 = v[3];
                    #pragma unroll
                    for (int i = 4; i < 16; i += 4) {
                        s0.x+=v[i].x;   s0.y+=v[i].y;   s0.z+=v[i].z;   s0.w+=v[i].w;
                        s1.x+=v[i+1].x; s1.y+=v[i+1].y; s1.z+=v[i+1].z; s1.w+=v[i+1].w;
                        s2.x+=v[i+2].x; s2.y+=v[i+2].y; s2.z+=v[i+2].z; s2.w+=v[i+2].w;
                        s3.x+=v[i+3].x; s3.y+=v[i+3].y; s3.z+=v[i+3].z; s3.w+=v[i+3].w;
                    }
                    a0 = (s0.x+s1.x) + (s2.x+s3.x);
                    a1 = (s0.y+s1.y) + (s2.y+s3.y);
                    a2 = (s0.z+s1.z) + (s2.z+s3.z);
                    a3 = (s0.w+s1.w) + (s2.w+s3.w);
                    ring[gl*64 + (t & 63)] = a0 + a1 + a2;
                }
                asm volatile("s_waitcnt lgkmcnt(0)" ::: "memory");
                if (m < nstep) {
                    float rv[LENF];
                    #pragma unroll
                    for (int k = 0; k < LENF; ++k)
                        rv[k] = ring[gl*64 + ((t - k) & 63)];
                    float accA = 0.f, accB = 0.f;
                    #pragma unroll
                    for (int k = 0; k < LENF-1; k += 2) {
                        accA = fmaf(wq[k],   rv[k],   accA);
                        accB = fmaf(wq[k+1], rv[k+1], accB);
                    }
                    accA = fmaf(wq[LENF-1], rv[LENF-1], accA);
                    float* ot = &outtile[m*OTW + gl*5];
                    ot[0] = accA + accB;
                    ot[1] = a0*inv16; ot[2] = a1*inv16;
                    ot[3] = a2*inv16; ot[4] = a3*inv16;
                }
                asm volatile("s_waitcnt lgkmcnt(0)" ::: "memory");
                const int ndw = nstep*20;
                float* ob = out + q*CH*7500 + b*40 + pipe*20;
                #pragma unroll
                for (int j = 0; j < 5; ++j) {
                    const int idx = lane + 64*j;
                    if (idx < ndw && st_ok[j]) ob[st_g[j]] = outtile[st_o[j]];
                }
            }
            if (do_stage) {
                float* xd = &xring[((p+1)%3)*CH*16];
                xd[lslot[0]] = stg0; xd[lslot[1]] = stg1; xd[lslot[2]] = stg2;
            }
            PIPE_BARRIER();
        }
    }
}

extern "C" void kernel_launch(void* const* d_in, const int* in_sizes, int n_in,
                              void* d_out, int out_size, void* d_ws, size_t ws_size,
                              hipStream_t stream)
{
    const float* x      = (const float*)d_in[0];
    const float* params = (const float*)d_in[1];
    const float* rt     = (const float*)d_in[2];
    float* out = (float*)d_out;

    dim3 grid((NGRID + 7) / 8), block(512);   // 188 blocks, 1 block/CU
    hipLaunchKernelGGL(hbv_scan_kernel, grid, block, 0, stream, x, params, rt, out);
}